// Round 17
// baseline (92.018 us; speedup 1.0000x reference)
//
#include <hip/hip_runtime.h>
#include <hip/hip_fp16.h>
#include <math.h>

// Problem: E=8, B=4096, D=128, N=8192.
// out[b,n] = softmax_n( x[b,:] @ W[e(b)] + bias[e(b)] ) for the (unique) bin e(b), else 0.
//
// Round 17 = R16 (85.9 us) + B-conversion amortization:
//   Each gemm block now owns a 256-row tile and processes it as TWO 128-row halves
//   serially, reusing the ONE B stage+convert (phase 1) and the in-register B
//   fragments for both halves. Per half: restage A into the same LDS, K-loop,
//   epilogue -- all byte-identical to R16's. Grid 64x40 -> 64x24; the per-block
//   64KB W read + 16K f2bf conversions drop 40% in aggregate. Early-exit skips
//   half 1 when cnt <= 128 (partial tiles). Same 512 thr / 34KB LDS / occupancy.
// Same f2bf rounding + K-loop -> absmax must stay exactly 1.220703e-4.
// Lessons kept: no min-waves launch_bounds (R3/R6); no per-lane gathered K-loop
// streams (R4); single-bf16 within threshold (R9); fp16 logit staging (R10);
// one change per round + revert path (R11-R16).

#define B_ROWS 4096
#define D_DIM  128
#define N_DIM  8192
#define E_NUM  8

typedef __attribute__((ext_vector_type(8))) __bf16 bf16x8;
typedef __attribute__((ext_vector_type(4))) float  f32x4;

__device__ __forceinline__ unsigned short f2bf(float f) {
    unsigned int u = __float_as_uint(f);
    unsigned int r = u + 0x7FFFu + ((u >> 16) & 1u);   // round-to-nearest-even
    return (unsigned short)(r >> 16);
}

// ws int layout:
//   [0]         n_tiles
//   [8..79]     tile_e
//   [96..167]   tile_start
//   [184..255]  tile_cnt
//   [448..455]  per-expert counts
//   [512..4607] sorted row indices (grouped by expert)

__global__ __launch_bounds__(1024)
void bin_kernel(const float* __restrict__ x,
                const float* __restrict__ tlo,
                const float* __restrict__ thi,
                int* __restrict__ ws_i, int m_tile) {
    __shared__ int cnt_s[E_NUM];
    __shared__ int off_s[E_NUM];
    __shared__ int cur_s[E_NUM];
    __shared__ int e_row[B_ROWS];

    int tid = threadIdx.x;
    if (tid < E_NUM) cnt_s[tid] = 0;
    __syncthreads();

    for (int r = tid; r < B_ROWS; r += 1024) {
        float th = x[(size_t)r * D_DIM];   // x[r, 0]
        int e = -1;
        #pragma unroll
        for (int i = 0; i < E_NUM; ++i) {
            if (e < 0 && th > tlo[i] && th <= thi[i]) e = i;  // first match
        }
        e_row[r] = e;
        if (e >= 0) atomicAdd(&cnt_s[e], 1);
    }
    __syncthreads();

    if (tid == 0) {
        int off = 0;
        for (int e = 0; e < E_NUM; ++e) {
            ws_i[448 + e] = cnt_s[e];
            off_s[e] = off;
            cur_s[e] = off;
            off += cnt_s[e];
        }
        int nt = 0;
        for (int e = 0; e < E_NUM; ++e) {
            int c = cnt_s[e];
            int s = off_s[e];
            for (int t0 = 0; t0 < c && nt < 72; t0 += m_tile) {
                ws_i[8 + nt]   = e;
                ws_i[96 + nt]  = s + t0;
                ws_i[184 + nt] = (c - t0 < m_tile) ? (c - t0) : m_tile;
                ++nt;
            }
        }
        ws_i[0] = nt;
    }
    __syncthreads();

    for (int r = tid; r < B_ROWS; r += 1024) {
        int e = e_row[r];
        if (e >= 0) {
            int p = atomicAdd(&cur_s[e], 1);
            ws_i[512 + p] = r;
        }
    }
}

// MFMA GEMM + inline W conversion, 2 row-halves per block:
//  1. stage B: W[e][d][n0..n0+128) fp32 -> bf16, transposed (136-pad + chunk-XOR)
//  2. each lane loads its 8 B fragments LDS -> regs
//  3. for each 128-row half of the 256-row tile:
//     restage A (fp32->bf16, byte-XOR swizzle) into the same LDS, K-loop, epilogue
//     (all byte-identical to R16; B frags persist in registers across halves)
__global__ __launch_bounds__(512)
void gemm_conv(const float* __restrict__ x,
               const float* __restrict__ W,
               const float* __restrict__ bias, const int* __restrict__ ws_i,
               float* __restrict__ out) {
    int bt = blockIdx.y;
    if (bt >= ws_i[0]) return;
    int e   = ws_i[8 + bt];
    int seg = ws_i[96 + bt];
    int cnt = ws_i[184 + bt];      // up to 256
    const int* sorted = ws_i + 512;

    __shared__ __align__(16) unsigned short s_buf[128 * 136];  // 34816 B, dual-use B->A

    int tid = threadIdx.x;
    int n0 = blockIdx.x * 128;

    // ---- phase 1: stage B slice fp32 -> bf16 transposed [col][d'] ----
    const float* Wp = W + (size_t)e * D_DIM * N_DIM + n0;
    #pragma unroll
    for (int i = 0; i < 8; ++i) {
        int idx = i * 512 + tid;          // 4096 float4 = 128 d-rows x 32 col-chunks
        int d  = idx >> 5;
        int c4 = idx & 31;
        float4 v = *(const float4*)(Wp + (size_t)d * N_DIM + c4 * 4);
        float fv[4] = {v.x, v.y, v.z, v.w};
        #pragma unroll
        for (int c = 0; c < 4; ++c) {
            int col = c4 * 4 + c;
            int dsw = d ^ (((col >> 2) & 7) << 3);   // chunk-XOR swizzle
            s_buf[col * 136 + dsw] = f2bf(fv[c]);
        }
    }
    __syncthreads();

    int lane = tid & 63;
    int wave = tid >> 6;            // wm = wave>>2 (64-row half), wn = wave&3 (32 cols)
    int wm = wave >> 2, wn = wave & 3;
    int l15 = lane & 15, q = lane >> 4;
    int colbase0 = wn * 32;
    int colbase  = n0 + colbase0;

    // ---- phase 2: this lane's 8 B fragment loads (LDS -> regs) ----
    bf16x8 b0[4], b1[4];
    #pragma unroll
    for (int s = 0; s < 4; ++s) {
        int d0 = s * 32 + q * 8;
        int c0 = colbase0 + l15;
        int c1 = colbase0 + 16 + l15;
        b0[s] = *(const bf16x8*)(&s_buf[c0 * 136 + (d0 ^ (((c0 >> 2) & 7) << 3))]);
        b1[s] = *(const bf16x8*)(&s_buf[c1 * 136 + (d0 ^ (((c1 >> 2) & 7) << 3))]);
    }

    const float* bp = bias + (size_t)e * N_DIM;
    float bv0 = bp[colbase + l15];
    float bv1 = bp[colbase + 16 + l15];

    unsigned short* a_s = s_buf;   // first 32768 B reused per half

    // ---- phase 3: two 128-row halves, B frags reused ----
    for (int h = 0; h < 2; ++h) {
        int base = h * 128;
        int cnt_h = cnt - base;
        if (cnt_h <= 0) break;
        int seg_h = seg + base;

        __syncthreads();   // previous phase's LDS reads (B frags / prior K-loop) done

        #pragma unroll
        for (int i = 0; i < 4; ++i) {
            int idx = i * 512 + tid;     // 2048 chunks = 128 rows x 16 x 16B(bf16)
            int row = idx >> 4;
            int ck  = idx & 15;
            unsigned short hq[8] = {0, 0, 0, 0, 0, 0, 0, 0};
            if (row < cnt_h) {
                int r = sorted[seg_h + row];
                const float* xp = x + (size_t)r * D_DIM + ck * 8;
                float4 va = *(const float4*)(xp);
                float4 vb = *(const float4*)(xp + 4);
                hq[0] = f2bf(va.x); hq[1] = f2bf(va.y); hq[2] = f2bf(va.z); hq[3] = f2bf(va.w);
                hq[4] = f2bf(vb.x); hq[5] = f2bf(vb.y); hq[6] = f2bf(vb.z); hq[7] = f2bf(vb.w);
            }
            int boff = row * 256 + ((ck * 16) ^ ((row & 7) << 4));
            *(uint4*)((char*)a_s + boff) = *(const uint4*)hq;
        }
        __syncthreads();

        f32x4 acc[4][2];
        #pragma unroll
        for (int mi = 0; mi < 4; ++mi) {
            acc[mi][0] = (f32x4){0.f, 0.f, 0.f, 0.f};
            acc[mi][1] = (f32x4){0.f, 0.f, 0.f, 0.f};
        }

        // K-loop (byte-identical to R16)
        #pragma unroll
        for (int s = 0; s < 4; ++s) {
            const int kb = (s * 32 + q * 8) * 2;   // byte offset in K
            #pragma unroll
            for (int mi = 0; mi < 4; ++mi) {
                int row  = wm * 64 + mi * 16 + l15;
                int aoff = row * 256 + (kb ^ ((row & 7) << 4));
                bf16x8 a = *(const bf16x8*)((const char*)a_s + aoff);
                acc[mi][0] = __builtin_amdgcn_mfma_f32_16x16x32_bf16(a, b0[s], acc[mi][0], 0, 0, 0);
                acc[mi][1] = __builtin_amdgcn_mfma_f32_16x16x32_bf16(a, b1[s], acc[mi][1], 0, 0, 0);
            }
        }

        // epilogue (byte-identical to R16): direct fp16 stores
        #pragma unroll
        for (int mi = 0; mi < 4; ++mi) {
            #pragma unroll
            for (int reg = 0; reg < 4; ++reg) {
                int m = wm * 64 + mi * 16 + q * 4 + reg;
                if (m < cnt_h) {
                    int r = sorted[seg_h + m];
                    __half* lp = (__half*)(out + (size_t)r * N_DIM);
                    lp[colbase + l15]      = __float2half(acc[mi][0][reg] + bv0);
                    lp[colbase + 16 + l15] = __float2half(acc[mi][1][reg] + bv1);
                }
            }
        }
    }
}

// Softmax over fp16 logits staged in the first 16KB of each 32KB fp32 row slot.
__global__ __launch_bounds__(256)
void softmax_f16(const float* __restrict__ x,
                 const float* __restrict__ tlo,
                 const float* __restrict__ thi,
                 float* __restrict__ out) {
    int r = blockIdx.x;
    int tid = threadIdx.x;
    float th = x[(size_t)r * D_DIM];
    bool valid = false;
    #pragma unroll
    for (int i = 0; i < E_NUM; ++i) {
        if (th > tlo[i] && th <= thi[i]) valid = true;
    }
    float* row = out + (size_t)r * N_DIM;

    if (!valid) {
        float4 z = make_float4(0.f, 0.f, 0.f, 0.f);
        #pragma unroll
        for (int c = 0; c < 4; ++c) {
            *(float4*)(row + c * 2048 + tid * 8)     = z;
            *(float4*)(row + c * 2048 + tid * 8 + 4) = z;
        }
        return;
    }

    float vv[32];
    float mx = -INFINITY;
    const __half* hp = (const __half*)row;
    #pragma unroll
    for (int c = 0; c < 4; ++c) {
        uint4 u = *(const uint4*)(hp + c * 2048 + tid * 8);
        const __half2* h2 = (const __half2*)&u;
        #pragma unroll
        for (int j = 0; j < 4; ++j) {
            float2 f = __half22float2(h2[j]);
            vv[c * 8 + 2 * j]     = f.x;
            vv[c * 8 + 2 * j + 1] = f.y;
            mx = fmaxf(mx, fmaxf(f.x, f.y));
        }
    }

    __shared__ float red[8];
    #pragma unroll
    for (int o = 1; o < 64; o <<= 1) mx = fmaxf(mx, __shfl_xor(mx, o));
    if ((tid & 63) == 0) red[tid >> 6] = mx;
    __syncthreads();
    mx = fmaxf(fmaxf(red[0], red[1]), fmaxf(red[2], red[3]));

    float sum = 0.f;
    #pragma unroll
    for (int i = 0; i < 32; ++i) {
        vv[i] = expf(vv[i] - mx);
        sum += vv[i];
    }
    #pragma unroll
    for (int o = 1; o < 64; o <<= 1) sum += __shfl_xor(sum, o);
    if ((tid & 63) == 0) red[4 + (tid >> 6)] = sum;
    __syncthreads();
    sum = red[4] + red[5] + red[6] + red[7];

    float inv = 1.0f / sum;
    #pragma unroll
    for (int c = 0; c < 4; ++c) {
        float4 o0, o1;
        o0.x = vv[c * 8 + 0] * inv; o0.y = vv[c * 8 + 1] * inv;
        o0.z = vv[c * 8 + 2] * inv; o0.w = vv[c * 8 + 3] * inv;
        o1.x = vv[c * 8 + 4] * inv; o1.y = vv[c * 8 + 5] * inv;
        o1.z = vv[c * 8 + 6] * inv; o1.w = vv[c * 8 + 7] * inv;
        *(float4*)(row + c * 2048 + tid * 8)     = o0;
        *(float4*)(row + c * 2048 + tid * 8 + 4) = o1;
    }
}

// ---------------- fallback path (workspace too small): bin + fp32 GEMM + softmax ------

__device__ __forceinline__ void fma4(float4& ac, float xs, const float4& wv) {
    ac.x = fmaf(xs, wv.x, ac.x);
    ac.y = fmaf(xs, wv.y, ac.y);
    ac.z = fmaf(xs, wv.z, ac.z);
    ac.w = fmaf(xs, wv.w, ac.w);
}

__global__ __launch_bounds__(256)
void gemm_kernel(const float* __restrict__ x,
                 const float* __restrict__ W,
                 const float* __restrict__ bias,
                 const int* __restrict__ ws_i,
                 float* __restrict__ out) {
    int bt = blockIdx.y;
    if (bt >= ws_i[0]) return;
    int e   = ws_i[8 + bt];
    int seg = ws_i[96 + bt];
    int cnt = ws_i[184 + bt];
    const int* sorted = ws_i + 512;

    __shared__ float x_s[64][D_DIM];
    __shared__ int   rows_s[64];

    int tid = threadIdx.x;
    if (tid < 64) rows_s[tid] = (tid < cnt) ? sorted[seg + tid] : -1;
    __syncthreads();

    #pragma unroll
    for (int c = 0; c < 8; ++c) {
        int idx = c * 256 + tid;
        int i = idx >> 5;
        int k4 = idx & 31;
        int r = rows_s[i];
        float4 v;
        if (r >= 0) v = *(const float4*)(x + (size_t)r * D_DIM + k4 * 4);
        else        v = make_float4(0.f, 0.f, 0.f, 0.f);
        *(float4*)(&x_s[i][k4 * 4]) = v;
    }
    __syncthreads();

    int nidx = tid & 63;
    int mg   = tid >> 6;
    int col  = blockIdx.x * 256 + nidx * 4;
    const float* Wp = W + ((size_t)e * D_DIM) * N_DIM + col;

    float4 acc[16];
    #pragma unroll
    for (int i = 0; i < 16; ++i) acc[i] = make_float4(0.f, 0.f, 0.f, 0.f);

    for (int k = 0; k < D_DIM; k += 4) {
        float4 w0 = *(const float4*)(Wp + (size_t)(k + 0) * N_DIM);
        float4 w1 = *(const float4*)(Wp + (size_t)(k + 1) * N_DIM);
        float4 w2 = *(const float4*)(Wp + (size_t)(k + 2) * N_DIM);
        float4 w3 = *(const float4*)(Wp + (size_t)(k + 3) * N_DIM);
        #pragma unroll
        for (int i = 0; i < 16; ++i) {
            float4 xv = *(const float4*)(&x_s[mg * 16 + i][k]);
            fma4(acc[i], xv.x, w0);
            fma4(acc[i], xv.y, w1);
            fma4(acc[i], xv.z, w2);
            fma4(acc[i], xv.w, w3);
        }
    }

    float4 bv = *(const float4*)(bias + (size_t)e * N_DIM + col);
    #pragma unroll
    for (int i = 0; i < 16; ++i) {
        int m = mg * 16 + i;
        if (m < cnt) {
            int r = rows_s[m];
            float4 o = acc[i];
            o.x += bv.x; o.y += bv.y; o.z += bv.z; o.w += bv.w;
            *(float4*)(out + (size_t)r * N_DIM + col) = o;
        }
    }
}

__global__ __launch_bounds__(256)
void softmax_kernel(const float* __restrict__ x,
                    const float* __restrict__ tlo,
                    const float* __restrict__ thi,
                    float* __restrict__ out) {
    int r = blockIdx.x;
    int tid = threadIdx.x;
    float th = x[(size_t)r * D_DIM];
    bool valid = false;
    #pragma unroll
    for (int i = 0; i < E_NUM; ++i) {
        if (th > tlo[i] && th <= thi[i]) valid = true;
    }
    float* row = out + (size_t)r * N_DIM;

    if (!valid) {
        float4 z = make_float4(0.f, 0.f, 0.f, 0.f);
        #pragma unroll
        for (int c = 0; c < 8; ++c)
            *(float4*)(row + c * 1024 + tid * 4) = z;
        return;
    }

    float4 v[8];
    float mx = -INFINITY;
    #pragma unroll
    for (int c = 0; c < 8; ++c) {
        v[c] = *(const float4*)(row + c * 1024 + tid * 4);
        mx = fmaxf(mx, fmaxf(fmaxf(v[c].x, v[c].y), fmaxf(v[c].z, v[c].w)));
    }

    __shared__ float red[8];
    #pragma unroll
    for (int o = 1; o < 64; o <<= 1) mx = fmaxf(mx, __shfl_xor(mx, o));
    if ((tid & 63) == 0) red[tid >> 6] = mx;
    __syncthreads();
    mx = fmaxf(fmaxf(red[0], red[1]), fmaxf(red[2], red[3]));

    float sum = 0.f;
    #pragma unroll
    for (int c = 0; c < 8; ++c) {
        v[c].x = expf(v[c].x - mx);
        v[c].y = expf(v[c].y - mx);
        v[c].z = expf(v[c].z - mx);
        v[c].w = expf(v[c].w - mx);
        sum += v[c].x + v[c].y + v[c].z + v[c].w;
    }
    #pragma unroll
    for (int o = 1; o < 64; o <<= 1) sum += __shfl_xor(sum, o);
    if ((tid & 63) == 0) red[4 + (tid >> 6)] = sum;
    __syncthreads();
    sum = red[4] + red[5] + red[6] + red[7];

    float inv = 1.0f / sum;
    #pragma unroll
    for (int c = 0; c < 8; ++c) {
        float4 o;
        o.x = v[c].x * inv; o.y = v[c].y * inv;
        o.z = v[c].z * inv; o.w = v[c].w * inv;
        *(float4*)(row + c * 1024 + tid * 4) = o;
    }
}

extern "C" void kernel_launch(void* const* d_in, const int* in_sizes, int n_in,
                              void* d_out, int out_size, void* d_ws, size_t ws_size,
                              hipStream_t stream) {
    const float* x   = (const float*)d_in[0];
    const float* W   = (const float*)d_in[1];
    const float* b   = (const float*)d_in[2];
    const float* tlo = (const float*)d_in[3];
    const float* thi = (const float*)d_in[4];
    float* out = (float*)d_out;
    int* ws_i = (int*)d_ws;

    bool fast = (ws_size >= 65536);   // only metadata needed

    if (fast) {
        bin_kernel<<<1, 1024, 0, stream>>>(x, tlo, thi, ws_i, 256);
        // tiles with m_tile=256: <= 16 full + 8 partials = 24
        gemm_conv<<<dim3(N_DIM / 128, 24), 512, 0, stream>>>(x, W, b, ws_i, out);
        softmax_f16<<<B_ROWS, 256, 0, stream>>>(x, tlo, thi, out);
    } else {
        bin_kernel<<<1, 1024, 0, stream>>>(x, tlo, thi, ws_i, 64);
        gemm_kernel<<<dim3(N_DIM / 256, 72), 256, 0, stream>>>(x, W, b, ws_i, out);
        softmax_kernel<<<B_ROWS, 256, 0, stream>>>(x, tlo, thi, out);
    }
}

// Round 18
// 85.891 us; speedup vs baseline: 1.0713x; 1.0713x over previous
//
#include <hip/hip_runtime.h>
#include <hip/hip_fp16.h>
#include <math.h>

// Problem: E=8, B=4096, D=128, N=8192.
// out[b,n] = softmax_n( x[b,:] @ W[e(b)] + bias[e(b)] ) for the (unique) bin e(b), else 0.
//
// Round 18 = REVERT to exact R16 (85.9 us best). R17's 2-half B-amortization regressed
// (92.0): halving block count + serializing two K-loops cost more than the L2-resident
// B rereads it saved -- same failure mode as R13. Twice-confirmed lesson: block-level
// parallelism > L2-traffic amortization in this regime.
// Pipeline: bin (1 block, 1024 thr) -> gemm_conv (inline W fp32->bf16 conversion,
// 128x128 tile, 512 thr, fp16 logit staging in-place) -> softmax_f16.
// absmax must stay exactly 1.220703e-4.
// Lessons: no min-waves launch_bounds (R3/R6); no per-lane gathered K-loop streams
// (R4); single-bf16 within threshold (R9); fp16 logits (R10); epilogue LDS staging
// hurts (R11); small bin block gates fusion (R12); bigger tiles hurt (R13/R17);
// bin-first fusion works (R15); convert-in-gemm works (R16).

#define B_ROWS 4096
#define D_DIM  128
#define N_DIM  8192
#define E_NUM  8

typedef __attribute__((ext_vector_type(8))) __bf16 bf16x8;
typedef __attribute__((ext_vector_type(4))) float  f32x4;

__device__ __forceinline__ unsigned short f2bf(float f) {
    unsigned int u = __float_as_uint(f);
    unsigned int r = u + 0x7FFFu + ((u >> 16) & 1u);   // round-to-nearest-even
    return (unsigned short)(r >> 16);
}

// ws int layout:
//   [0]         n_tiles
//   [8..79]     tile_e
//   [96..167]   tile_start
//   [184..255]  tile_cnt
//   [448..455]  per-expert counts
//   [512..4607] sorted row indices (grouped by expert)

__global__ __launch_bounds__(1024)
void bin_kernel(const float* __restrict__ x,
                const float* __restrict__ tlo,
                const float* __restrict__ thi,
                int* __restrict__ ws_i, int m_tile) {
    __shared__ int cnt_s[E_NUM];
    __shared__ int off_s[E_NUM];
    __shared__ int cur_s[E_NUM];
    __shared__ int e_row[B_ROWS];

    int tid = threadIdx.x;
    if (tid < E_NUM) cnt_s[tid] = 0;
    __syncthreads();

    for (int r = tid; r < B_ROWS; r += 1024) {
        float th = x[(size_t)r * D_DIM];   // x[r, 0]
        int e = -1;
        #pragma unroll
        for (int i = 0; i < E_NUM; ++i) {
            if (e < 0 && th > tlo[i] && th <= thi[i]) e = i;  // first match
        }
        e_row[r] = e;
        if (e >= 0) atomicAdd(&cnt_s[e], 1);
    }
    __syncthreads();

    if (tid == 0) {
        int off = 0;
        for (int e = 0; e < E_NUM; ++e) {
            ws_i[448 + e] = cnt_s[e];
            off_s[e] = off;
            cur_s[e] = off;
            off += cnt_s[e];
        }
        int nt = 0;
        for (int e = 0; e < E_NUM; ++e) {
            int c = cnt_s[e];
            int s = off_s[e];
            for (int t0 = 0; t0 < c && nt < 72; t0 += m_tile) {
                ws_i[8 + nt]   = e;
                ws_i[96 + nt]  = s + t0;
                ws_i[184 + nt] = (c - t0 < m_tile) ? (c - t0) : m_tile;
                ++nt;
            }
        }
        ws_i[0] = nt;
    }
    __syncthreads();

    for (int r = tid; r < B_ROWS; r += 1024) {
        int e = e_row[r];
        if (e >= 0) {
            int p = atomicAdd(&cur_s[e], 1);
            ws_i[512 + p] = r;
        }
    }
}

// MFMA GEMM + inline W conversion: block = 128 rows x 128 cols, 512 threads = 8 waves
// in 2x4 split; wave = 64 rows x 32 cols, acc[4][2]. Phases:
//  1. stage B: W[e][d][n0..n0+128) fp32 -> bf16, transposed into 34KB LDS
//     (136-pad + chunk-XOR layout)
//  2. each lane loads its 8 B fragments LDS -> regs (16B-aligned contiguous reads)
//  3. REUSE LDS: stage gathered A rows (fp32->bf16, byte-XOR swizzle)
//  4. K-loop + fp16 epilogue (direct stores, barrier-free wave drain).
__global__ __launch_bounds__(512)
void gemm_conv(const float* __restrict__ x,
               const float* __restrict__ W,
               const float* __restrict__ bias, const int* __restrict__ ws_i,
               float* __restrict__ out) {
    int bt = blockIdx.y;
    if (bt >= ws_i[0]) return;
    int e   = ws_i[8 + bt];
    int seg = ws_i[96 + bt];
    int cnt = ws_i[184 + bt];
    const int* sorted = ws_i + 512;

    __shared__ __align__(16) unsigned short s_buf[128 * 136];  // 34816 B, dual-use B->A

    int tid = threadIdx.x;
    int n0 = blockIdx.x * 128;

    // ---- phase 1: stage B slice fp32 -> bf16 transposed [col][d'] ----
    const float* Wp = W + (size_t)e * D_DIM * N_DIM + n0;
    #pragma unroll
    for (int i = 0; i < 8; ++i) {
        int idx = i * 512 + tid;          // 4096 float4 = 128 d-rows x 32 col-chunks
        int d  = idx >> 5;
        int c4 = idx & 31;
        float4 v = *(const float4*)(Wp + (size_t)d * N_DIM + c4 * 4);
        float fv[4] = {v.x, v.y, v.z, v.w};
        #pragma unroll
        for (int c = 0; c < 4; ++c) {
            int col = c4 * 4 + c;
            int dsw = d ^ (((col >> 2) & 7) << 3);   // chunk-XOR swizzle
            s_buf[col * 136 + dsw] = f2bf(fv[c]);
        }
    }
    __syncthreads();

    int lane = tid & 63;
    int wave = tid >> 6;            // wm = wave>>2 (64-row half), wn = wave&3 (32 cols)
    int wm = wave >> 2, wn = wave & 3;
    int l15 = lane & 15, q = lane >> 4;
    int colbase0 = wn * 32;
    int colbase  = n0 + colbase0;

    // ---- phase 2: this lane's 8 B fragment loads (LDS -> regs) ----
    // fragment (col, d0..d0+8): stored at col*136 + (d ^ swz(col)); swz is a multiple
    // of 8 and d0 is a multiple of 8, so the 8 elements stay 16B-contiguous.
    bf16x8 b0[4], b1[4];
    #pragma unroll
    for (int s = 0; s < 4; ++s) {
        int d0 = s * 32 + q * 8;
        int c0 = colbase0 + l15;
        int c1 = colbase0 + 16 + l15;
        b0[s] = *(const bf16x8*)(&s_buf[c0 * 136 + (d0 ^ (((c0 >> 2) & 7) << 3))]);
        b1[s] = *(const bf16x8*)(&s_buf[c1 * 136 + (d0 ^ (((c1 >> 2) & 7) << 3))]);
    }
    __syncthreads();   // all B reads done before A overwrites the buffer

    // ---- phase 3: stage gathered A rows (fp32->bf16), byte-XOR swizzle ----
    unsigned short* a_s = s_buf;   // first 32768 B reused
    #pragma unroll
    for (int i = 0; i < 4; ++i) {
        int idx = i * 512 + tid;     // 2048 chunks = 128 rows x 16 x 16B(bf16)
        int row = idx >> 4;
        int ck  = idx & 15;
        unsigned short hq[8] = {0, 0, 0, 0, 0, 0, 0, 0};
        if (row < cnt) {
            int r = sorted[seg + row];
            const float* xp = x + (size_t)r * D_DIM + ck * 8;
            float4 va = *(const float4*)(xp);
            float4 vb = *(const float4*)(xp + 4);
            hq[0] = f2bf(va.x); hq[1] = f2bf(va.y); hq[2] = f2bf(va.z); hq[3] = f2bf(va.w);
            hq[4] = f2bf(vb.x); hq[5] = f2bf(vb.y); hq[6] = f2bf(vb.z); hq[7] = f2bf(vb.w);
        }
        int boff = row * 256 + ((ck * 16) ^ ((row & 7) << 4));
        *(uint4*)((char*)a_s + boff) = *(const uint4*)hq;
    }
    __syncthreads();   // K-loop + epilogue barrier-free from here

    f32x4 acc[4][2];
    #pragma unroll
    for (int mi = 0; mi < 4; ++mi) {
        acc[mi][0] = (f32x4){0.f, 0.f, 0.f, 0.f};
        acc[mi][1] = (f32x4){0.f, 0.f, 0.f, 0.f};
    }

    // ---- phase 4: K-loop ----
    #pragma unroll
    for (int s = 0; s < 4; ++s) {
        const int kb = (s * 32 + q * 8) * 2;   // byte offset in K
        #pragma unroll
        for (int mi = 0; mi < 4; ++mi) {
            int row  = wm * 64 + mi * 16 + l15;
            int aoff = row * 256 + (kb ^ ((row & 7) << 4));
            bf16x8 a = *(const bf16x8*)((const char*)a_s + aoff);
            acc[mi][0] = __builtin_amdgcn_mfma_f32_16x16x32_bf16(a, b0[s], acc[mi][0], 0, 0, 0);
            acc[mi][1] = __builtin_amdgcn_mfma_f32_16x16x32_bf16(a, b1[s], acc[mi][1], 0, 0, 0);
        }
    }

    // epilogue: C/D layout col=lane&15, row=(lane>>4)*4+reg.
    // Direct fp16 stores into the first N_DIM halfs of the row's fp32 slot.
    const float* bp = bias + (size_t)e * N_DIM;
    float bv0 = bp[colbase + l15];
    float bv1 = bp[colbase + 16 + l15];

    #pragma unroll
    for (int mi = 0; mi < 4; ++mi) {
        #pragma unroll
        for (int reg = 0; reg < 4; ++reg) {
            int m = wm * 64 + mi * 16 + q * 4 + reg;
            if (m < cnt) {
                int r = sorted[seg + m];
                __half* lp = (__half*)(out + (size_t)r * N_DIM);
                lp[colbase + l15]      = __float2half(acc[mi][0][reg] + bv0);
                lp[colbase + 16 + l15] = __float2half(acc[mi][1][reg] + bv1);
            }
        }
    }
}

// Softmax over fp16 logits staged in the first 16KB of each 32KB fp32 row slot.
__global__ __launch_bounds__(256)
void softmax_f16(const float* __restrict__ x,
                 const float* __restrict__ tlo,
                 const float* __restrict__ thi,
                 float* __restrict__ out) {
    int r = blockIdx.x;
    int tid = threadIdx.x;
    float th = x[(size_t)r * D_DIM];
    bool valid = false;
    #pragma unroll
    for (int i = 0; i < E_NUM; ++i) {
        if (th > tlo[i] && th <= thi[i]) valid = true;
    }
    float* row = out + (size_t)r * N_DIM;

    if (!valid) {
        float4 z = make_float4(0.f, 0.f, 0.f, 0.f);
        #pragma unroll
        for (int c = 0; c < 4; ++c) {
            *(float4*)(row + c * 2048 + tid * 8)     = z;
            *(float4*)(row + c * 2048 + tid * 8 + 4) = z;
        }
        return;
    }

    float vv[32];
    float mx = -INFINITY;
    const __half* hp = (const __half*)row;
    #pragma unroll
    for (int c = 0; c < 4; ++c) {
        uint4 u = *(const uint4*)(hp + c * 2048 + tid * 8);
        const __half2* h2 = (const __half2*)&u;
        #pragma unroll
        for (int j = 0; j < 4; ++j) {
            float2 f = __half22float2(h2[j]);
            vv[c * 8 + 2 * j]     = f.x;
            vv[c * 8 + 2 * j + 1] = f.y;
            mx = fmaxf(mx, fmaxf(f.x, f.y));
        }
    }

    __shared__ float red[8];
    #pragma unroll
    for (int o = 1; o < 64; o <<= 1) mx = fmaxf(mx, __shfl_xor(mx, o));
    if ((tid & 63) == 0) red[tid >> 6] = mx;
    __syncthreads();
    mx = fmaxf(fmaxf(red[0], red[1]), fmaxf(red[2], red[3]));

    float sum = 0.f;
    #pragma unroll
    for (int i = 0; i < 32; ++i) {
        vv[i] = expf(vv[i] - mx);
        sum += vv[i];
    }
    #pragma unroll
    for (int o = 1; o < 64; o <<= 1) sum += __shfl_xor(sum, o);
    if ((tid & 63) == 0) red[4 + (tid >> 6)] = sum;
    __syncthreads();
    sum = red[4] + red[5] + red[6] + red[7];

    float inv = 1.0f / sum;
    #pragma unroll
    for (int c = 0; c < 4; ++c) {
        float4 o0, o1;
        o0.x = vv[c * 8 + 0] * inv; o0.y = vv[c * 8 + 1] * inv;
        o0.z = vv[c * 8 + 2] * inv; o0.w = vv[c * 8 + 3] * inv;
        o1.x = vv[c * 8 + 4] * inv; o1.y = vv[c * 8 + 5] * inv;
        o1.z = vv[c * 8 + 6] * inv; o1.w = vv[c * 8 + 7] * inv;
        *(float4*)(row + c * 2048 + tid * 8)     = o0;
        *(float4*)(row + c * 2048 + tid * 8 + 4) = o1;
    }
}

// ---------------- fallback path (workspace too small): bin + fp32 GEMM + softmax ------

__device__ __forceinline__ void fma4(float4& ac, float xs, const float4& wv) {
    ac.x = fmaf(xs, wv.x, ac.x);
    ac.y = fmaf(xs, wv.y, ac.y);
    ac.z = fmaf(xs, wv.z, ac.z);
    ac.w = fmaf(xs, wv.w, ac.w);
}

__global__ __launch_bounds__(256)
void gemm_kernel(const float* __restrict__ x,
                 const float* __restrict__ W,
                 const float* __restrict__ bias,
                 const int* __restrict__ ws_i,
                 float* __restrict__ out) {
    int bt = blockIdx.y;
    if (bt >= ws_i[0]) return;
    int e   = ws_i[8 + bt];
    int seg = ws_i[96 + bt];
    int cnt = ws_i[184 + bt];
    const int* sorted = ws_i + 512;

    __shared__ float x_s[64][D_DIM];
    __shared__ int   rows_s[64];

    int tid = threadIdx.x;
    if (tid < 64) rows_s[tid] = (tid < cnt) ? sorted[seg + tid] : -1;
    __syncthreads();

    #pragma unroll
    for (int c = 0; c < 8; ++c) {
        int idx = c * 256 + tid;
        int i = idx >> 5;
        int k4 = idx & 31;
        int r = rows_s[i];
        float4 v;
        if (r >= 0) v = *(const float4*)(x + (size_t)r * D_DIM + k4 * 4);
        else        v = make_float4(0.f, 0.f, 0.f, 0.f);
        *(float4*)(&x_s[i][k4 * 4]) = v;
    }
    __syncthreads();

    int nidx = tid & 63;
    int mg   = tid >> 6;
    int col  = blockIdx.x * 256 + nidx * 4;
    const float* Wp = W + ((size_t)e * D_DIM) * N_DIM + col;

    float4 acc[16];
    #pragma unroll
    for (int i = 0; i < 16; ++i) acc[i] = make_float4(0.f, 0.f, 0.f, 0.f);

    for (int k = 0; k < D_DIM; k += 4) {
        float4 w0 = *(const float4*)(Wp + (size_t)(k + 0) * N_DIM);
        float4 w1 = *(const float4*)(Wp + (size_t)(k + 1) * N_DIM);
        float4 w2 = *(const float4*)(Wp + (size_t)(k + 2) * N_DIM);
        float4 w3 = *(const float4*)(Wp + (size_t)(k + 3) * N_DIM);
        #pragma unroll
        for (int i = 0; i < 16; ++i) {
            float4 xv = *(const float4*)(&x_s[mg * 16 + i][k]);
            fma4(acc[i], xv.x, w0);
            fma4(acc[i], xv.y, w1);
            fma4(acc[i], xv.z, w2);
            fma4(acc[i], xv.w, w3);
        }
    }

    float4 bv = *(const float4*)(bias + (size_t)e * N_DIM + col);
    #pragma unroll
    for (int i = 0; i < 16; ++i) {
        int m = mg * 16 + i;
        if (m < cnt) {
            int r = rows_s[m];
            float4 o = acc[i];
            o.x += bv.x; o.y += bv.y; o.z += bv.z; o.w += bv.w;
            *(float4*)(out + (size_t)r * N_DIM + col) = o;
        }
    }
}

__global__ __launch_bounds__(256)
void softmax_kernel(const float* __restrict__ x,
                    const float* __restrict__ tlo,
                    const float* __restrict__ thi,
                    float* __restrict__ out) {
    int r = blockIdx.x;
    int tid = threadIdx.x;
    float th = x[(size_t)r * D_DIM];
    bool valid = false;
    #pragma unroll
    for (int i = 0; i < E_NUM; ++i) {
        if (th > tlo[i] && th <= thi[i]) valid = true;
    }
    float* row = out + (size_t)r * N_DIM;

    if (!valid) {
        float4 z = make_float4(0.f, 0.f, 0.f, 0.f);
        #pragma unroll
        for (int c = 0; c < 8; ++c)
            *(float4*)(row + c * 1024 + tid * 4) = z;
        return;
    }

    float4 v[8];
    float mx = -INFINITY;
    #pragma unroll
    for (int c = 0; c < 8; ++c) {
        v[c] = *(const float4*)(row + c * 1024 + tid * 4);
        mx = fmaxf(mx, fmaxf(fmaxf(v[c].x, v[c].y), fmaxf(v[c].z, v[c].w)));
    }

    __shared__ float red[8];
    #pragma unroll
    for (int o = 1; o < 64; o <<= 1) mx = fmaxf(mx, __shfl_xor(mx, o));
    if ((tid & 63) == 0) red[tid >> 6] = mx;
    __syncthreads();
    mx = fmaxf(fmaxf(red[0], red[1]), fmaxf(red[2], red[3]));

    float sum = 0.f;
    #pragma unroll
    for (int c = 0; c < 8; ++c) {
        v[c].x = expf(v[c].x - mx);
        v[c].y = expf(v[c].y - mx);
        v[c].z = expf(v[c].z - mx);
        v[c].w = expf(v[c].w - mx);
        sum += v[c].x + v[c].y + v[c].z + v[c].w;
    }
    #pragma unroll
    for (int o = 1; o < 64; o <<= 1) sum += __shfl_xor(sum, o);
    if ((tid & 63) == 0) red[4 + (tid >> 6)] = sum;
    __syncthreads();
    sum = red[4] + red[5] + red[6] + red[7];

    float inv = 1.0f / sum;
    #pragma unroll
    for (int c = 0; c < 8; ++c) {
        float4 o;
        o.x = v[c].x * inv; o.y = v[c].y * inv;
        o.z = v[c].z * inv; o.w = v[c].w * inv;
        *(float4*)(row + c * 1024 + tid * 4) = o;
    }
}

extern "C" void kernel_launch(void* const* d_in, const int* in_sizes, int n_in,
                              void* d_out, int out_size, void* d_ws, size_t ws_size,
                              hipStream_t stream) {
    const float* x   = (const float*)d_in[0];
    const float* W   = (const float*)d_in[1];
    const float* b   = (const float*)d_in[2];
    const float* tlo = (const float*)d_in[3];
    const float* thi = (const float*)d_in[4];
    float* out = (float*)d_out;
    int* ws_i = (int*)d_ws;

    bool fast = (ws_size >= 65536);   // only metadata needed

    if (fast) {
        bin_kernel<<<1, 1024, 0, stream>>>(x, tlo, thi, ws_i, 128);
        // tiles <= 32 full + 8 partials = 40
        gemm_conv<<<dim3(N_DIM / 128, 40), 512, 0, stream>>>(x, W, b, ws_i, out);
        softmax_f16<<<B_ROWS, 256, 0, stream>>>(x, tlo, thi, out);
    } else {
        bin_kernel<<<1, 1024, 0, stream>>>(x, tlo, thi, ws_i, 64);
        gemm_kernel<<<dim3(N_DIM / 256, 72), 256, 0, stream>>>(x, W, b, ws_i, out);
        softmax_kernel<<<B_ROWS, 256, 0, stream>>>(x, tlo, thi, out);
    }
}